// Round 6
// baseline (124.708 us; speedup 1.0000x reference)
//
#include <hip/hip_runtime.h>
#include <hip/hip_bf16.h>
#include <stdint.h>

typedef float  f32x4   __attribute__((ext_vector_type(4)));
typedef float  f32x16  __attribute__((ext_vector_type(16)));
typedef __bf16 bf16x8  __attribute__((ext_vector_type(8)));
typedef __bf16 bf16x4  __attribute__((ext_vector_type(4)));
typedef uint32_t u32x4 __attribute__((ext_vector_type(4)));

#define LOG2E 1.44269504088896340736f

__device__ __forceinline__ f32x4 mfma16(bf16x8 a, bf16x8 b, f32x4 c) {
    return __builtin_amdgcn_mfma_f32_16x16x32_bf16(a, b, c, 0, 0, 0);
}
__device__ __forceinline__ f32x16 mfma32(bf16x8 a, bf16x8 b, f32x16 c) {
    return __builtin_amdgcn_mfma_f32_32x32x16_bf16(a, b, c, 0, 0, 0);
}

__device__ __forceinline__ float fast_exp2(float x) {
#if __has_builtin(__builtin_amdgcn_exp2f)
    return __builtin_amdgcn_exp2f(x);
#else
    return exp2f(x);
#endif
}

// packed f32x2 -> bf16x2 (RNE); D = {hi:bf16(s1), lo:bf16(s0)}
__device__ __forceinline__ uint32_t cvt_pk_bf16(float lo, float hi) {
    uint32_t r;
    asm("v_cvt_pk_bf16_f32 %0, %1, %2" : "=v"(r) : "v"(lo), "v"(hi));
    return r;
}
// D[lanes 32..63] <-> S[lanes 0..31]; both operands modified
__device__ __forceinline__ void perm32swap(uint32_t& a, uint32_t& b) {
    asm("v_permlane32_swap_b32 %0, %1" : "+v"(a), "+v"(b));
}

// async global->LDS, 16B per lane (wave-uniform base + lane*16 dest).
__device__ __forceinline__ void gload16(const void* g, void* lds) {
    __builtin_amdgcn_global_load_lds(
        (const __attribute__((address_space(1))) uint32_t*)g,
        (__attribute__((address_space(3))) uint32_t*)lds, 16, 0, 0);
}

// ---------------- fused cast(hs)+avgpool: one read of hs ----------------
__global__ void cast_pool_kernel(const float* __restrict__ hs,
                                 __bf16* __restrict__ hsb,
                                 __bf16* __restrict__ poolb, int n) {
    int i = blockIdx.x * blockDim.x + threadIdx.x;
    if (i >= n) return;
    int j = i >> 7;
    int c = (i & 127) * 8;
    int b = j >> 10, t = j & 1023;
    size_t rowg = (size_t)(b * 4096 + t * 4);
    const float* base = hs + (rowg << 10) + c;
    float sum[8];
#pragma unroll
    for (int e = 0; e < 8; ++e) sum[e] = 0.f;
#pragma unroll
    for (int r = 0; r < 4; ++r) {
        float4 a = *(const float4*)(base + (size_t)r * 1024);
        float4 d = *(const float4*)(base + (size_t)r * 1024 + 4);
        bf16x8 o;
        o[0] = (__bf16)a.x; o[1] = (__bf16)a.y; o[2] = (__bf16)a.z; o[3] = (__bf16)a.w;
        o[4] = (__bf16)d.x; o[5] = (__bf16)d.y; o[6] = (__bf16)d.z; o[7] = (__bf16)d.w;
        *reinterpret_cast<bf16x8*>(hsb + ((rowg + r) << 10) + c) = o;
        sum[0] += a.x; sum[1] += a.y; sum[2] += a.z; sum[3] += a.w;
        sum[4] += d.x; sum[5] += d.y; sum[6] += d.z; sum[7] += d.w;
    }
    bf16x8 p;
#pragma unroll
    for (int e = 0; e < 8; ++e) p[e] = (__bf16)(sum[e] * 0.25f);
    *reinterpret_cast<bf16x8*>(poolb + ((size_t)j << 10) + c) = p;
}

// ---------------- all three weight casts in one launch ----------------
__global__ void cast_w_kernel(const float* __restrict__ Wq, const float* __restrict__ Wk,
                              const float* __restrict__ Wv, __bf16* __restrict__ wqb,
                              __bf16* __restrict__ wkvb, float qscale, int n) {
    int i = blockIdx.x * blockDim.x + threadIdx.x;
    if (i >= n) return;
    const float* src; __bf16* dst; float sc; int j;
    if (i < 131072)      { src = Wq; dst = wqb;            sc = qscale; j = i; }
    else if (i < 262144) { src = Wk; dst = wkvb;           sc = 1.f;    j = i - 131072; }
    else                 { src = Wv; dst = wkvb + 1048576; sc = 1.f;    j = i - 262144; }
    const float4* s = reinterpret_cast<const float4*>(src) + (size_t)j * 2;
    float4 a = s[0], b = s[1];
    bf16x8 o;
    o[0] = (__bf16)(a.x * sc); o[1] = (__bf16)(a.y * sc);
    o[2] = (__bf16)(a.z * sc); o[3] = (__bf16)(a.w * sc);
    o[4] = (__bf16)(b.x * sc); o[5] = (__bf16)(b.y * sc);
    o[6] = (__bf16)(b.z * sc); o[7] = (__bf16)(b.w * sc);
    *reinterpret_cast<bf16x8*>(dst + (size_t)j * 8) = o;
}

// ---------------- pooled mask -> additive log2-domain bias ----------------
__global__ void mask_kernel(const int* __restrict__ mask,
                            float* __restrict__ mb, int n) {
    int i = blockIdx.x * blockDim.x + threadIdx.x;
    if (i >= n) return;
    int b = i >> 10, j = i & 1023;
    const int* p = mask + b * 4096 + j * 4;
    int any = p[0] | p[1] | p[2] | p[3];
    mb[i] = any ? (-10000.0f * LOG2E) : 0.0f;
}

// ---------------- fused Q + KV GEMM (unchanged) ----------------
__global__ __launch_bounds__(256)
void gemm_fused(const __bf16* __restrict__ hsb, const __bf16* __restrict__ poolb,
                const __bf16* __restrict__ wqb, const __bf16* __restrict__ wkvb,
                const float* __restrict__ bq, const float* __restrict__ bk,
                const float* __restrict__ bv, float qscale,
                __bf16* __restrict__ qb, __bf16* __restrict__ kb,
                __bf16* __restrict__ vtb) {
    __shared__ __bf16 As[128 * 64];
    __shared__ __bf16 Bs[128 * 64];
    const int tid  = threadIdx.x;
    const int lane = tid & 63, wid = tid >> 6;
    const int lg = lane >> 4, l15 = lane & 15;
    const int wm = (wid >> 1) * 64, wn = (wid & 1) * 64;

    const int id = blockIdx.x;
    const bool isQ = (id < 512);
    const int bx = isQ ? (id & 63) : ((id - 512) & 15);
    const int by = isQ ? (id >> 6) : ((id - 512) >> 4);
    const __bf16* A = isQ ? hsb : poolb;
    const __bf16* W = isQ ? wqb : wkvb;
    const int rowBase = bx * 128, colBase = by * 128;

    const f32x4 zero = {0.f, 0.f, 0.f, 0.f};
    f32x4 acc[4][4];
#pragma unroll
    for (int m = 0; m < 4; ++m)
#pragma unroll
        for (int n = 0; n < 4; ++n) acc[m][n] = zero;

    const char* Ag = (const char*)(A + (size_t)rowBase * 1024);
    const char* Wg = (const char*)(W + (size_t)colBase * 1024);
    char* AsB = (char*)As;
    char* BsB = (char*)Bs;

    const char* ag[4]; const char* wg[4]; int ld[4];
#pragma unroll
    for (int p = 0; p < 4; ++p) {
        int o  = p * 4096 + tid * 16;
        int r  = o >> 7, cb = o & 127;
        int cs = cb ^ ((r & 7) << 4);
        ag[p] = Ag + (size_t)r * 2048 + cs;
        wg[p] = Wg + (size_t)r * 2048 + cs;
        ld[p] = o;
    }

    for (int kt = 0; kt < 16; ++kt) {
        const int k0b = kt * 128;
        __syncthreads();
#pragma unroll
        for (int p = 0; p < 4; ++p) {
            gload16(ag[p] + k0b, AsB + ld[p]);
            gload16(wg[p] + k0b, BsB + ld[p]);
        }
        __syncthreads();

        bf16x8 af[4][2], bfr[4][2];
#pragma unroll
        for (int m = 0; m < 4; ++m)
#pragma unroll
            for (int kk = 0; kk < 2; ++kk) {
                int r  = wm + m * 16 + l15;
                int cb = kk * 64 + lg * 16;
                af[m][kk] = *(const bf16x8*)(AsB + r * 128 + (cb ^ ((r & 7) << 4)));
            }
#pragma unroll
        for (int n = 0; n < 4; ++n)
#pragma unroll
            for (int kk = 0; kk < 2; ++kk) {
                int r  = wn + n * 16 + l15;
                int cb = kk * 64 + lg * 16;
                bfr[n][kk] = *(const bf16x8*)(BsB + r * 128 + (cb ^ ((r & 7) << 4)));
            }
#pragma unroll
        for (int m = 0; m < 4; ++m)
#pragma unroll
            for (int n = 0; n < 4; ++n) {
                acc[m][n] = mfma16(af[m][0], bfr[n][0], acc[m][n]);
                acc[m][n] = mfma16(af[m][1], bfr[n][1], acc[m][n]);
            }
    }

#pragma unroll
    for (int m = 0; m < 4; ++m)
#pragma unroll
        for (int n = 0; n < 4; ++n) {
            int col  = colBase + wn + n * 16 + l15;
            int row0 = rowBase + wm + m * 16 + lg * 4;
            if (isQ) {
                float bvl = bq[col] * qscale;
#pragma unroll
                for (int reg = 0; reg < 4; ++reg)
                    qb[(size_t)(row0 + reg) * 1024 + col] = (__bf16)(acc[m][n][reg] + bvl);
            } else if (col < 1024) {
                float bvl = bk[col];
#pragma unroll
                for (int reg = 0; reg < 4; ++reg)
                    kb[(size_t)(row0 + reg) * 1024 + col] = (__bf16)(acc[m][n][reg] + bvl);
            } else {
                float bvl = bv[col - 1024];
                int bb   = row0 >> 10;
                int key0 = row0 & 1023;
                bf16x4 o;
#pragma unroll
                for (int reg = 0; reg < 4; ++reg) o[reg] = (__bf16)(acc[m][n][reg] + bvl);
                *reinterpret_cast<bf16x4*>(vtb + (((size_t)(bb * 1024 + (col - 1024))) << 10) + key0) = o;
            }
        }
}

// ---------------- flash attention: 32x32x16 MFMA, in-register P via cvt_pk+permlane ----------------
// EXACT round-4 computation (verified absmax 1.95e-3); ONLY change: launch_bounds
// (256,2)->(256,1) so the allocator doesn't cap at 128 VGPRs and spill (round-4
// post-mortem: WRITE_SIZE 32768->38912 KB scratch traffic was the regression).
// At <=256 VGPR: 2 waves/SIMD -> 8 waves/CU -> 2 blocks/CU (matches 512-block grid).
__global__ __launch_bounds__(256, 1)
void attn_kernel(const __bf16* __restrict__ Q, const __bf16* __restrict__ K,
                 const __bf16* __restrict__ Vt, const float* __restrict__ mb,
                 float* __restrict__ out) {
    __shared__ __bf16 Ks[2][64 * 64];
    __shared__ __bf16 Vs[2][64 * 64];
    const int tid  = threadIdx.x;
    const int lane = tid & 63, wid = tid >> 6;
    const int l31 = lane & 31, hi = lane >> 5;

    // XCD-aware bijective swizzle (512 blocks, 64 consecutive per XCD)
    const int lin = blockIdx.x + blockIdx.y * 16;
    const int nid = (lin & 7) * 64 + (lin >> 3);
    const int qi = nid & 15, bh = nid >> 4;
    const int b = bh >> 4, h = bh & 15;
    const int qbase = qi * 256 + wid * 64;

    // Q B-frags: [qt][ds], col=q=l31, k(hi*8+j) at d = ds*16+hi*8
    bf16x8 qf[2][4];
#pragma unroll
    for (int qt = 0; qt < 2; ++qt)
#pragma unroll
        for (int ds = 0; ds < 4; ++ds)
            qf[qt][ds] = *(const bf16x8*)(Q + (((size_t)(b * 4096 + qbase + qt * 32 + l31)) << 10)
                                          + h * 64 + ds * 16 + hi * 8);

    f32x16 acc[2][2];
#pragma unroll
    for (int qt = 0; qt < 2; ++qt)
#pragma unroll
        for (int dt = 0; dt < 2; ++dt)
#pragma unroll
            for (int r = 0; r < 16; ++r) acc[qt][dt][r] = 0.f;
    float rs[2] = {0.f, 0.f};

    const char* Kg = (const char*)(K + (((size_t)(b * 1024)) << 10) + h * 64);
    const char* Vg = (const char*)(Vt + (((size_t)(b * 1024 + h * 64)) << 10));
    const float* mbp = mb + b * 1024;

    const char* kg[2]; const char* vg[2]; int ld[2];
#pragma unroll
    for (int p = 0; p < 2; ++p) {
        int o  = p * 4096 + tid * 16;
        int r  = o >> 7, cb = o & 127;
        int cs = cb ^ ((r & 7) << 4);
        kg[p] = Kg + (size_t)r * 2048 + cs;
        vg[p] = Vg + (size_t)r * 2048 + cs;
        ld[p] = o;
    }

#pragma unroll
    for (int p = 0; p < 2; ++p) {
        gload16(kg[p], (char*)Ks[0] + ld[p]);
        gload16(vg[p], (char*)Vs[0] + ld[p]);
    }

    int cur = 0;
    for (int kt = 0; kt < 16; ++kt) {
        __syncthreads();   // buf[cur] ready (vmcnt drained at barrier), buf[cur^1] free
        if (kt < 15) {
#pragma unroll
            for (int p = 0; p < 2; ++p) {
                gload16(kg[p] + (size_t)(kt + 1) * 131072, (char*)Ks[cur ^ 1] + ld[p]);
                gload16(vg[p] + (kt + 1) * 128,            (char*)Vs[cur ^ 1] + ld[p]);
            }
        }
        const char* KsB = (const char*)Ks[cur];
        const char* VsB = (const char*)Vs[cur];

        // K A-frags: row=key=nt*32+l31, k at d=ds*16+hi*8  (reused across both qt)
        bf16x8 kf[2][4];
#pragma unroll
        for (int nt = 0; nt < 2; ++nt)
#pragma unroll
            for (int ds = 0; ds < 4; ++ds) {
                int row = nt * 32 + l31;
                kf[nt][ds] = *(const bf16x8*)(KsB + row * 128 + ((ds * 32 + hi * 16) ^ ((row & 7) << 4)));
            }

        u32x4 pf[2][4];   // P A-frags per qt, 4 key-slices of 16
#pragma unroll
        for (int qt = 0; qt < 2; ++qt) {
#pragma unroll
            for (int nt = 0; nt < 2; ++nt) {
                f32x16 s;
#pragma unroll
                for (int r = 0; r < 16; ++r) s[r] = 0.f;
#pragma unroll
                for (int ds = 0; ds < 4; ++ds) s = mfma32(kf[nt][ds], qf[qt][ds], s);

                // mask per reg r: key = nt*32 + (r>>2)*8 + (r&3) + 4*hi
                const float* mbase = mbp + kt * 64 + nt * 32 + hi * 4;
                float p[16];
#pragma unroll
                for (int i = 0; i < 4; ++i) {
                    float4 mv = *(const float4*)(mbase + i * 8);
                    p[i * 4 + 0] = fast_exp2(s[i * 4 + 0] + mv.x);
                    p[i * 4 + 1] = fast_exp2(s[i * 4 + 1] + mv.y);
                    p[i * 4 + 2] = fast_exp2(s[i * 4 + 2] + mv.z);
                    p[i * 4 + 3] = fast_exp2(s[i * 4 + 3] + mv.w);
                }
                float t0 = (p[0] + p[1]) + (p[2] + p[3]);
                float t1 = (p[4] + p[5]) + (p[6] + p[7]);
                float t2 = (p[8] + p[9]) + (p[10] + p[11]);
                float t3 = (p[12] + p[13]) + (p[14] + p[15]);
                rs[qt] += (t0 + t1) + (t2 + t3);

                // pack pairs: c[i] = keys(2i,2i+1)+4hi of this nt-tile
                uint32_t c0 = cvt_pk_bf16(p[0], p[1]),   c1 = cvt_pk_bf16(p[2], p[3]);
                uint32_t c2 = cvt_pk_bf16(p[4], p[5]),   c3 = cvt_pk_bf16(p[6], p[7]);
                uint32_t c4 = cvt_pk_bf16(p[8], p[9]),   c5 = cvt_pk_bf16(p[10], p[11]);
                uint32_t c6 = cvt_pk_bf16(p[12], p[13]), c7 = cvt_pk_bf16(p[14], p[15]);
                // redistribute halves across lane<32 / lane>=32
                perm32swap(c0, c2); perm32swap(c1, c3);
                perm32swap(c4, c6); perm32swap(c5, c7);
                u32x4 lo4 = {c0, c1, c2, c3};
                u32x4 hi4 = {c4, c5, c6, c7};
                pf[qt][nt * 2 + 0] = lo4;
                pf[qt][nt * 2 + 1] = hi4;
            }
        }

        // PV: acc[qt][dt] += P[qt][ks] x V[ks][dt]   (V B-frag: col=d=l31, k=key)
#pragma unroll
        for (int dt = 0; dt < 2; ++dt)
#pragma unroll
            for (int ks = 0; ks < 4; ++ks) {
                int row = dt * 32 + l31;
                bf16x8 vb = *(const bf16x8*)(VsB + row * 128 + ((ks * 32 + hi * 16) ^ ((row & 7) << 4)));
#pragma unroll
                for (int qt = 0; qt < 2; ++qt)
                    acc[qt][dt] = mfma32(__builtin_bit_cast(bf16x8, pf[qt][ks]), vb, acc[qt][dt]);
            }
        cur ^= 1;
    }

    // final row sums: lanes q and q+32 hold partials for q = l31
#pragma unroll
    for (int qt = 0; qt < 2; ++qt) rs[qt] += __shfl_xor(rs[qt], 32);

    // epilogue: out row q = (r&3)+8*(r>>2)+4*hi, col = dt*32 + l31 (coalesced)
#pragma unroll
    for (int qt = 0; qt < 2; ++qt)
#pragma unroll
        for (int r = 0; r < 16; ++r) {
            int ql = (r & 3) + 8 * (r >> 2) + 4 * hi;
            float inv = 1.0f / __shfl(rs[qt], ql);
            size_t row = (size_t)(b * 4096 + qbase + qt * 32 + ql);
#pragma unroll
            for (int dt = 0; dt < 2; ++dt)
                out[(row << 10) + h * 64 + dt * 32 + l31] = acc[qt][dt][r] * inv;
        }
}

extern "C" void kernel_launch(void* const* d_in, const int* in_sizes, int n_in,
                              void* d_out, int out_size, void* d_ws, size_t ws_size,
                              hipStream_t stream) {
    const float* hs    = (const float*)d_in[0];
    const int*   amask = (const int*)d_in[1];
    const float* Wq    = (const float*)d_in[2];
    const float* bq    = (const float*)d_in[3];
    const float* Wk    = (const float*)d_in[4];
    const float* bk    = (const float*)d_in[5];
    const float* Wv    = (const float*)d_in[6];
    const float* bv    = (const float*)d_in[7];
    float* out = (float*)d_out;

    char* ws = (char*)d_ws;
    size_t off = 0;
    auto alloc = [&](size_t bytes) -> char* {
        char* p = ws + off;
        off += (bytes + 255) & ~(size_t)255;
        return p;
    };
    __bf16* hsb   = (__bf16*)alloc(8388608ull * 2);  // hidden bf16 [8192][1024]
    __bf16* qb    = (__bf16*)alloc(8388608ull * 2);  // Q bf16 (pre-scaled)
    __bf16* poolb = (__bf16*)alloc(2097152ull * 2);  // pooled bf16 [2048][1024]
    __bf16* kb    = (__bf16*)alloc(2097152ull * 2);  // K bf16
    __bf16* vtb   = (__bf16*)alloc(2097152ull * 2);  // V^T bf16 [b,h,d][key]
    __bf16* wqb   = (__bf16*)alloc(1048576ull * 2);  // Wq * qscale
    __bf16* wkvb  = (__bf16*)alloc(2097152ull * 2);  // [Wk ; Wv]
    float*  mbf   = (float*)alloc(2048 * 4);

    const float qscale = 0.125f * LOG2E;   // 1/sqrt(DH) and log2(e) folded into Q

    cast_pool_kernel<<<1024, 256, 0, stream>>>(hs, hsb, poolb, 262144);
    cast_w_kernel<<<1536, 256, 0, stream>>>(Wq, Wk, Wv, wqb, wkvb, qscale, 393216);
    mask_kernel<<<8, 256, 0, stream>>>(amask, mbf, 2048);

    gemm_fused<<<768, 256, 0, stream>>>(hsb, poolb, wqb, wkvb, bq, bk, bv, qscale,
                                        qb, kb, vtb);

    attn_kernel<<<dim3(16, 32), 256, 0, stream>>>(qb, kb, vtb, mbf, out);
}

// Round 7
// 115.151 us; speedup vs baseline: 1.0830x; 1.0830x over previous
//
#include <hip/hip_runtime.h>
#include <hip/hip_bf16.h>
#include <stdint.h>

typedef float  f32x4   __attribute__((ext_vector_type(4)));
typedef __bf16 bf16x8  __attribute__((ext_vector_type(8)));
typedef __bf16 bf16x4  __attribute__((ext_vector_type(4)));

#define LOG2E 1.44269504088896340736f

__device__ __forceinline__ f32x4 mfma16(bf16x8 a, bf16x8 b, f32x4 c) {
    return __builtin_amdgcn_mfma_f32_16x16x32_bf16(a, b, c, 0, 0, 0);
}

__device__ __forceinline__ float fast_exp2(float x) {
#if __has_builtin(__builtin_amdgcn_exp2f)
    return __builtin_amdgcn_exp2f(x);
#else
    return exp2f(x);
#endif
}

// async global->LDS, 16B per lane (wave-uniform base + lane*16 dest).
__device__ __forceinline__ void gload16(const void* g, void* lds) {
    __builtin_amdgcn_global_load_lds(
        (const __attribute__((address_space(1))) uint32_t*)g,
        (__attribute__((address_space(3))) uint32_t*)lds, 16, 0, 0);
}

// ---------------- fused cast(hs)+avgpool: one read of hs ----------------
__global__ void cast_pool_kernel(const float* __restrict__ hs,
                                 __bf16* __restrict__ hsb,
                                 __bf16* __restrict__ poolb, int n) {
    int i = blockIdx.x * blockDim.x + threadIdx.x;
    if (i >= n) return;
    int j = i >> 7;
    int c = (i & 127) * 8;
    int b = j >> 10, t = j & 1023;
    size_t rowg = (size_t)(b * 4096 + t * 4);
    const float* base = hs + (rowg << 10) + c;
    float sum[8];
#pragma unroll
    for (int e = 0; e < 8; ++e) sum[e] = 0.f;
#pragma unroll
    for (int r = 0; r < 4; ++r) {
        float4 a = *(const float4*)(base + (size_t)r * 1024);
        float4 d = *(const float4*)(base + (size_t)r * 1024 + 4);
        bf16x8 o;
        o[0] = (__bf16)a.x; o[1] = (__bf16)a.y; o[2] = (__bf16)a.z; o[3] = (__bf16)a.w;
        o[4] = (__bf16)d.x; o[5] = (__bf16)d.y; o[6] = (__bf16)d.z; o[7] = (__bf16)d.w;
        *reinterpret_cast<bf16x8*>(hsb + ((rowg + r) << 10) + c) = o;
        sum[0] += a.x; sum[1] += a.y; sum[2] += a.z; sum[3] += a.w;
        sum[4] += d.x; sum[5] += d.y; sum[6] += d.z; sum[7] += d.w;
    }
    bf16x8 p;
#pragma unroll
    for (int e = 0; e < 8; ++e) p[e] = (__bf16)(sum[e] * 0.25f);
    *reinterpret_cast<bf16x8*>(poolb + ((size_t)j << 10) + c) = p;
}

// ---------------- all three weight casts in one launch ----------------
__global__ void cast_w_kernel(const float* __restrict__ Wq, const float* __restrict__ Wk,
                              const float* __restrict__ Wv, __bf16* __restrict__ wqb,
                              __bf16* __restrict__ wkvb, float qscale, int n) {
    int i = blockIdx.x * blockDim.x + threadIdx.x;
    if (i >= n) return;
    const float* src; __bf16* dst; float sc; int j;
    if (i < 131072)      { src = Wq; dst = wqb;            sc = qscale; j = i; }
    else if (i < 262144) { src = Wk; dst = wkvb;           sc = 1.f;    j = i - 131072; }
    else                 { src = Wv; dst = wkvb + 1048576; sc = 1.f;    j = i - 262144; }
    const float4* s = reinterpret_cast<const float4*>(src) + (size_t)j * 2;
    float4 a = s[0], b = s[1];
    bf16x8 o;
    o[0] = (__bf16)(a.x * sc); o[1] = (__bf16)(a.y * sc);
    o[2] = (__bf16)(a.z * sc); o[3] = (__bf16)(a.w * sc);
    o[4] = (__bf16)(b.x * sc); o[5] = (__bf16)(b.y * sc);
    o[6] = (__bf16)(b.z * sc); o[7] = (__bf16)(b.w * sc);
    *reinterpret_cast<bf16x8*>(dst + (size_t)j * 8) = o;
}

// ---------------- pooled mask -> additive log2-domain bias ----------------
__global__ void mask_kernel(const int* __restrict__ mask,
                            float* __restrict__ mb, int n) {
    int i = blockIdx.x * blockDim.x + threadIdx.x;
    if (i >= n) return;
    int b = i >> 10, j = i & 1023;
    const int* p = mask + b * 4096 + j * 4;
    int any = p[0] | p[1] | p[2] | p[3];
    mb[i] = any ? (-10000.0f * LOG2E) : 0.0f;
}

// ---------------- fused Q + KV GEMM (unchanged) ----------------
__global__ __launch_bounds__(256)
void gemm_fused(const __bf16* __restrict__ hsb, const __bf16* __restrict__ poolb,
                const __bf16* __restrict__ wqb, const __bf16* __restrict__ wkvb,
                const float* __restrict__ bq, const float* __restrict__ bk,
                const float* __restrict__ bv, float qscale,
                __bf16* __restrict__ qb, __bf16* __restrict__ kb,
                __bf16* __restrict__ vtb) {
    __shared__ __bf16 As[128 * 64];
    __shared__ __bf16 Bs[128 * 64];
    const int tid  = threadIdx.x;
    const int lane = tid & 63, wid = tid >> 6;
    const int lg = lane >> 4, l15 = lane & 15;
    const int wm = (wid >> 1) * 64, wn = (wid & 1) * 64;

    const int id = blockIdx.x;
    const bool isQ = (id < 512);
    const int bx = isQ ? (id & 63) : ((id - 512) & 15);
    const int by = isQ ? (id >> 6) : ((id - 512) >> 4);
    const __bf16* A = isQ ? hsb : poolb;
    const __bf16* W = isQ ? wqb : wkvb;
    const int rowBase = bx * 128, colBase = by * 128;

    const f32x4 zero = {0.f, 0.f, 0.f, 0.f};
    f32x4 acc[4][4];
#pragma unroll
    for (int m = 0; m < 4; ++m)
#pragma unroll
        for (int n = 0; n < 4; ++n) acc[m][n] = zero;

    const char* Ag = (const char*)(A + (size_t)rowBase * 1024);
    const char* Wg = (const char*)(W + (size_t)colBase * 1024);
    char* AsB = (char*)As;
    char* BsB = (char*)Bs;

    const char* ag[4]; const char* wg[4]; int ld[4];
#pragma unroll
    for (int p = 0; p < 4; ++p) {
        int o  = p * 4096 + tid * 16;
        int r  = o >> 7, cb = o & 127;
        int cs = cb ^ ((r & 7) << 4);
        ag[p] = Ag + (size_t)r * 2048 + cs;
        wg[p] = Wg + (size_t)r * 2048 + cs;
        ld[p] = o;
    }

    for (int kt = 0; kt < 16; ++kt) {
        const int k0b = kt * 128;
        __syncthreads();
#pragma unroll
        for (int p = 0; p < 4; ++p) {
            gload16(ag[p] + k0b, AsB + ld[p]);
            gload16(wg[p] + k0b, BsB + ld[p]);
        }
        __syncthreads();

        bf16x8 af[4][2], bfr[4][2];
#pragma unroll
        for (int m = 0; m < 4; ++m)
#pragma unroll
            for (int kk = 0; kk < 2; ++kk) {
                int r  = wm + m * 16 + l15;
                int cb = kk * 64 + lg * 16;
                af[m][kk] = *(const bf16x8*)(AsB + r * 128 + (cb ^ ((r & 7) << 4)));
            }
#pragma unroll
        for (int n = 0; n < 4; ++n)
#pragma unroll
            for (int kk = 0; kk < 2; ++kk) {
                int r  = wn + n * 16 + l15;
                int cb = kk * 64 + lg * 16;
                bfr[n][kk] = *(const bf16x8*)(BsB + r * 128 + (cb ^ ((r & 7) << 4)));
            }
#pragma unroll
        for (int m = 0; m < 4; ++m)
#pragma unroll
            for (int n = 0; n < 4; ++n) {
                acc[m][n] = mfma16(af[m][0], bfr[n][0], acc[m][n]);
                acc[m][n] = mfma16(af[m][1], bfr[n][1], acc[m][n]);
            }
    }

#pragma unroll
    for (int m = 0; m < 4; ++m)
#pragma unroll
        for (int n = 0; n < 4; ++n) {
            int col  = colBase + wn + n * 16 + l15;
            int row0 = rowBase + wm + m * 16 + lg * 4;
            if (isQ) {
                float bvl = bq[col] * qscale;
#pragma unroll
                for (int reg = 0; reg < 4; ++reg)
                    qb[(size_t)(row0 + reg) * 1024 + col] = (__bf16)(acc[m][n][reg] + bvl);
            } else if (col < 1024) {
                float bvl = bk[col];
#pragma unroll
                for (int reg = 0; reg < 4; ++reg)
                    kb[(size_t)(row0 + reg) * 1024 + col] = (__bf16)(acc[m][n][reg] + bvl);
            } else {
                float bvl = bv[col - 1024];
                int bb   = row0 >> 10;
                int key0 = row0 & 1023;
                bf16x4 o;
#pragma unroll
                for (int reg = 0; reg < 4; ++reg) o[reg] = (__bf16)(acc[m][n][reg] + bvl);
                *reinterpret_cast<bf16x4*>(vtb + (((size_t)(bb * 1024 + (col - 1024))) << 10) + key0) = o;
            }
        }
}

// ---------------- flash attention: round-3 verified structure, occupancy-tuned ----------------
// 16x16x32 MFMA, LDS-P (verified absmax 1.95e-3 at 64 q/wave). ONE change vs r3:
// 32 q/wave (128 q/block), grid 32x32 = 1024 blocks = 4 blocks/CU; LDS 48 KB ->
// 3 blocks resident (12 waves/CU, +50% vs r3's 8). launch_bounds(256,3) caps
// VGPR at 170 (working set ~140 -> no spill; r4 lesson: watch WRITE_SIZE==32768).
__global__ __launch_bounds__(256, 3)
void attn_kernel(const __bf16* __restrict__ Q, const __bf16* __restrict__ K,
                 const __bf16* __restrict__ Vt, const float* __restrict__ mb,
                 float* __restrict__ out) {
    __shared__ __bf16 Ks[2][64 * 64];
    __shared__ __bf16 Vs[2][64 * 64];
    __shared__ __bf16 Ps[4][32 * 64];
    const int tid  = threadIdx.x;
    const int lane = tid & 63, wid = tid >> 6;
    const int lg = lane >> 4, l15 = lane & 15;

    // XCD-aware bijective swizzle: 1024 blocks, 128 consecutive per XCD
    // -> 4 heads' K/V (1 MB) per XCD L2.
    const int lin = blockIdx.x + blockIdx.y * 32;
    const int nid = (lin & 7) * 128 + (lin >> 3);
    const int qi = nid & 31, bh = nid >> 5;
    const int b = bh >> 4, h = bh & 15;
    const int qbase = qi * 128 + wid * 32;

    // Q fragments: 2 sub-tiles of 16 q rows (A layout: row=l15, k=lg*8+j)
    bf16x8 aq[2][2];
#pragma unroll
    for (int qm = 0; qm < 2; ++qm) {
        const __bf16* qrow = Q + (((size_t)(b * 4096 + qbase + qm * 16 + l15)) << 10) + h * 64;
        aq[qm][0] = *(const bf16x8*)(qrow + lg * 8);
        aq[qm][1] = *(const bf16x8*)(qrow + 32 + lg * 8);
    }

    const f32x4 zero = {0.f, 0.f, 0.f, 0.f};
    f32x4 acc[2][4];
#pragma unroll
    for (int qm = 0; qm < 2; ++qm)
#pragma unroll
        for (int n = 0; n < 4; ++n) acc[qm][n] = zero;
    float rs[2] = {0.f, 0.f};

    const char* Kg = (const char*)(K + (((size_t)(b * 1024)) << 10) + h * 64);
    const char* Vg = (const char*)(Vt + (((size_t)(b * 1024 + h * 64)) << 10));
    const float* mbp = mb + b * 1024;

    char* PsB = (char*)Ps[wid];
    const int pswz = (l15 & 7) << 4;

    const char* kg[2]; const char* vg[2]; int ld[2];
#pragma unroll
    for (int p = 0; p < 2; ++p) {
        int o  = p * 4096 + tid * 16;
        int r  = o >> 7, cb = o & 127;
        int cs = cb ^ ((r & 7) << 4);
        kg[p] = Kg + (size_t)r * 2048 + cs;
        vg[p] = Vg + (size_t)r * 2048 + cs;
        ld[p] = o;
    }

#pragma unroll
    for (int p = 0; p < 2; ++p) {
        gload16(kg[p], (char*)Ks[0] + ld[p]);
        gload16(vg[p], (char*)Vs[0] + ld[p]);
    }

    int cur = 0;
    for (int kt = 0; kt < 16; ++kt) {
        __syncthreads();   // buf[cur] ready (vmcnt drained at barrier), buf[cur^1] free
        if (kt < 15) {
#pragma unroll
            for (int p = 0; p < 2; ++p) {
                gload16(kg[p] + (size_t)(kt + 1) * 131072, (char*)Ks[cur ^ 1] + ld[p]);
                gload16(vg[p] + (kt + 1) * 128,            (char*)Vs[cur ^ 1] + ld[p]);
            }
        }
        const char* KsB = (const char*)Ks[cur];
        const char* VsB = (const char*)Vs[cur];

        // K fragments (reused across both q sub-tiles)
        bf16x8 bk[4][2];
#pragma unroll
        for (int n = 0; n < 4; ++n)
#pragma unroll
            for (int kk = 0; kk < 2; ++kk) {
                int key = n * 16 + l15;
                bk[n][kk] = *(const bf16x8*)(KsB + key * 128 + ((kk * 64 + lg * 16) ^ ((key & 7) << 4)));
            }
        f32x4 mv[4];
#pragma unroll
        for (int n = 0; n < 4; ++n) mv[n] = *(const f32x4*)(mbp + kt * 64 + n * 16 + lg * 4);

        // per q sub-tile: S^T = K·Q^T (col=q=l15, row=key=lg*4+reg), exp2, write P
#pragma unroll
        for (int qm = 0; qm < 2; ++qm) {
            f32x4 s[4];
#pragma unroll
            for (int n = 0; n < 4; ++n) {
                s[n] = mfma16(bk[n][0], aq[qm][0], zero);
                s[n] = mfma16(bk[n][1], aq[qm][1], s[n]);
            }
            const int prow = (qm * 16 + l15) * 128;
#pragma unroll
            for (int n = 0; n < 4; ++n) {
                float p0 = fast_exp2(s[n][0] + mv[n][0]);
                float p1 = fast_exp2(s[n][1] + mv[n][1]);
                float p2 = fast_exp2(s[n][2] + mv[n][2]);
                float p3 = fast_exp2(s[n][3] + mv[n][3]);
                rs[qm] += (p0 + p1) + (p2 + p3);
                bf16x4 o;
                o[0] = (__bf16)p0; o[1] = (__bf16)p1; o[2] = (__bf16)p2; o[3] = (__bf16)p3;
                *(bf16x4*)(PsB + prow + ((n * 32 + lg * 8) ^ pswz)) = o;
            }
        }

        // V fragments (reused across both q sub-tiles)
        bf16x8 bv[4][2];
#pragma unroll
        for (int n = 0; n < 4; ++n)
#pragma unroll
            for (int kk = 0; kk < 2; ++kk) {
                int d = n * 16 + l15;
                bv[n][kk] = *(const bf16x8*)(VsB + d * 128 + ((kk * 64 + lg * 16) ^ ((d & 7) << 4)));
            }
#pragma unroll
        for (int qm = 0; qm < 2; ++qm) {
            const int prow = (qm * 16 + l15) * 128;
            bf16x8 ap0 = *(const bf16x8*)(PsB + prow + ((lg * 16) ^ pswz));
            bf16x8 ap1 = *(const bf16x8*)(PsB + prow + ((64 + lg * 16) ^ pswz));
#pragma unroll
            for (int n = 0; n < 4; ++n) {
                acc[qm][n] = mfma16(ap0, bv[n][0], acc[qm][n]);
                acc[qm][n] = mfma16(ap1, bv[n][1], acc[qm][n]);
            }
        }
        cur ^= 1;
    }

    // reduce row sums over the 4 lane-groups, redistribute to epilogue layout
    float inv[2][4];
#pragma unroll
    for (int qm = 0; qm < 2; ++qm) {
        rs[qm] += __shfl_xor(rs[qm], 16);
        rs[qm] += __shfl_xor(rs[qm], 32);
#pragma unroll
        for (int r = 0; r < 4; ++r) inv[qm][r] = 1.0f / __shfl(rs[qm], lg * 4 + r);
    }

#pragma unroll
    for (int qm = 0; qm < 2; ++qm)
#pragma unroll
        for (int n = 0; n < 4; ++n)
#pragma unroll
            for (int r = 0; r < 4; ++r) {
                size_t row = (size_t)(b * 4096 + qbase + qm * 16 + lg * 4 + r);
                out[(row << 10) + h * 64 + n * 16 + l15] = acc[qm][n][r] * inv[qm][r];
            }
}

extern "C" void kernel_launch(void* const* d_in, const int* in_sizes, int n_in,
                              void* d_out, int out_size, void* d_ws, size_t ws_size,
                              hipStream_t stream) {
    const float* hs    = (const float*)d_in[0];
    const int*   amask = (const int*)d_in[1];
    const float* Wq    = (const float*)d_in[2];
    const float* bq    = (const float*)d_in[3];
    const float* Wk    = (const float*)d_in[4];
    const float* bk    = (const float*)d_in[5];
    const float* Wv    = (const float*)d_in[6];
    const float* bv    = (const float*)d_in[7];
    float* out = (float*)d_out;

    char* ws = (char*)d_ws;
    size_t off = 0;
    auto alloc = [&](size_t bytes) -> char* {
        char* p = ws + off;
        off += (bytes + 255) & ~(size_t)255;
        return p;
    };
    __bf16* hsb   = (__bf16*)alloc(8388608ull * 2);  // hidden bf16 [8192][1024]
    __bf16* qb    = (__bf16*)alloc(8388608ull * 2);  // Q bf16 (pre-scaled)
    __bf16* poolb = (__bf16*)alloc(2097152ull * 2);  // pooled bf16 [2048][1024]
    __bf16* kb    = (__bf16*)alloc(2097152ull * 2);  // K bf16
    __bf16* vtb   = (__bf16*)alloc(2097152ull * 2);  // V^T bf16 [b,h,d][key]
    __bf16* wqb   = (__bf16*)alloc(1048576ull * 2);  // Wq * qscale
    __bf16* wkvb  = (__bf16*)alloc(2097152ull * 2);  // [Wk ; Wv]
    float*  mbf   = (float*)alloc(2048 * 4);

    const float qscale = 0.125f * LOG2E;   // 1/sqrt(DH) and log2(e) folded into Q

    cast_pool_kernel<<<1024, 256, 0, stream>>>(hs, hsb, poolb, 262144);
    cast_w_kernel<<<1536, 256, 0, stream>>>(Wq, Wk, Wv, wqb, wkvb, qscale, 393216);
    mask_kernel<<<8, 256, 0, stream>>>(amask, mbf, 2048);

    gemm_fused<<<768, 256, 0, stream>>>(hsb, poolb, wqb, wkvb, bq, bk, bv, qscale,
                                        qb, kb, vtb);

    attn_kernel<<<dim3(32, 32), 256, 0, stream>>>(qb, kb, vtb, mbf, out);
}

// Round 8
// 68.859 us; speedup vs baseline: 1.8111x; 1.6723x over previous
//
#include <hip/hip_runtime.h>
#include <hip/hip_bf16.h>
#include <stdint.h>

typedef float  f32x4   __attribute__((ext_vector_type(4)));
typedef __bf16 bf16x8  __attribute__((ext_vector_type(8)));
typedef __bf16 bf16x4  __attribute__((ext_vector_type(4)));

#define LOG2E 1.44269504088896340736f

__device__ __forceinline__ f32x4 mfma16(bf16x8 a, bf16x8 b, f32x4 c) {
    return __builtin_amdgcn_mfma_f32_16x16x32_bf16(a, b, c, 0, 0, 0);
}

__device__ __forceinline__ float fast_exp2(float x) {
#if __has_builtin(__builtin_amdgcn_exp2f)
    return __builtin_amdgcn_exp2f(x);
#else
    return exp2f(x);
#endif
}

// async global->LDS, 16B per lane (wave-uniform base + lane*16 dest).
__device__ __forceinline__ void gload16(const void* g, void* lds) {
    __builtin_amdgcn_global_load_lds(
        (const __attribute__((address_space(1))) uint32_t*)g,
        (__attribute__((address_space(3))) uint32_t*)lds, 16, 0, 0);
}

// ---------------- fused cast(hs)+avgpool: one read of hs ----------------
__global__ void cast_pool_kernel(const float* __restrict__ hs,
                                 __bf16* __restrict__ hsb,
                                 __bf16* __restrict__ poolb, int n) {
    int i = blockIdx.x * blockDim.x + threadIdx.x;
    if (i >= n) return;
    int j = i >> 7;
    int c = (i & 127) * 8;
    int b = j >> 10, t = j & 1023;
    size_t rowg = (size_t)(b * 4096 + t * 4);
    const float* base = hs + (rowg << 10) + c;
    float sum[8];
#pragma unroll
    for (int e = 0; e < 8; ++e) sum[e] = 0.f;
#pragma unroll
    for (int r = 0; r < 4; ++r) {
        float4 a = *(const float4*)(base + (size_t)r * 1024);
        float4 d = *(const float4*)(base + (size_t)r * 1024 + 4);
        bf16x8 o;
        o[0] = (__bf16)a.x; o[1] = (__bf16)a.y; o[2] = (__bf16)a.z; o[3] = (__bf16)a.w;
        o[4] = (__bf16)d.x; o[5] = (__bf16)d.y; o[6] = (__bf16)d.z; o[7] = (__bf16)d.w;
        *reinterpret_cast<bf16x8*>(hsb + ((rowg + r) << 10) + c) = o;
        sum[0] += a.x; sum[1] += a.y; sum[2] += a.z; sum[3] += a.w;
        sum[4] += d.x; sum[5] += d.y; sum[6] += d.z; sum[7] += d.w;
    }
    bf16x8 p;
#pragma unroll
    for (int e = 0; e < 8; ++e) p[e] = (__bf16)(sum[e] * 0.25f);
    *reinterpret_cast<bf16x8*>(poolb + ((size_t)j << 10) + c) = p;
}

// ---------------- all three weight casts in one launch ----------------
__global__ void cast_w_kernel(const float* __restrict__ Wq, const float* __restrict__ Wk,
                              const float* __restrict__ Wv, __bf16* __restrict__ wqb,
                              __bf16* __restrict__ wkvb, float qscale, int n) {
    int i = blockIdx.x * blockDim.x + threadIdx.x;
    if (i >= n) return;
    const float* src; __bf16* dst; float sc; int j;
    if (i < 131072)      { src = Wq; dst = wqb;            sc = qscale; j = i; }
    else if (i < 262144) { src = Wk; dst = wkvb;           sc = 1.f;    j = i - 131072; }
    else                 { src = Wv; dst = wkvb + 1048576; sc = 1.f;    j = i - 262144; }
    const float4* s = reinterpret_cast<const float4*>(src) + (size_t)j * 2;
    float4 a = s[0], b = s[1];
    bf16x8 o;
    o[0] = (__bf16)(a.x * sc); o[1] = (__bf16)(a.y * sc);
    o[2] = (__bf16)(a.z * sc); o[3] = (__bf16)(a.w * sc);
    o[4] = (__bf16)(b.x * sc); o[5] = (__bf16)(b.y * sc);
    o[6] = (__bf16)(b.z * sc); o[7] = (__bf16)(b.w * sc);
    *reinterpret_cast<bf16x8*>(dst + (size_t)j * 8) = o;
}

// ---------------- mask scan: compact unmasked pooled keys ----------------
// Bucket j of batch b is unmasked iff mask[b*4096 + 4j .. 4j+3] are all 0.
// Masked keys get -10000 additive bias -> exp underflows to EXACTLY 0 in f32
// (reference does the same after max-subtraction), so computing only unmasked
// keys is bit-exact. Fallback cnt==0: identity list + sscale=0 -> P=1 uniform
// (reference: softmax of all-equal scores = uniform). meta[b*4+{0,1,2,3}] =
// {cnt_final, ntiles, cntp64, sscale_bits}.
__global__ void maskscan_kernel(const int* __restrict__ mask,
                                int* __restrict__ idxl,     // [2][1024]
                                float* __restrict__ bias_c, // [2][1024]
                                int* __restrict__ meta) {
    const int b = blockIdx.x;
    const int t = threadIdx.x;   // 256 threads, 4 buckets each
    __shared__ int ps[256];
    __shared__ int totsh;
    int f[4];
    const int4* mp = (const int4*)(mask + b * 4096 + t * 16);
#pragma unroll
    for (int i = 0; i < 4; ++i) {
        int4 v = mp[i];
        f[i] = ((v.x | v.y | v.z | v.w) == 0) ? 1 : 0;
    }
    int c = f[0] + f[1] + f[2] + f[3];
    ps[t] = c;
    __syncthreads();
    for (int off = 1; off < 256; off <<= 1) {
        int v = (t >= off) ? ps[t - off] : 0;
        __syncthreads();
        ps[t] += v;
        __syncthreads();
    }
    int excl = ps[t] - c;
    if (t == 255) totsh = ps[255];
    __syncthreads();
    int cnt = totsh;
    int e = excl;
#pragma unroll
    for (int i = 0; i < 4; ++i)
        if (f[i]) idxl[b * 1024 + (e++)] = t * 4 + i;
    int cntf = cnt ? cnt : 1024;
    if (cnt == 0) {
#pragma unroll
        for (int i = 0; i < 4; ++i) idxl[b * 1024 + t * 4 + i] = t * 4 + i;
    }
    int ntiles = (cntf + 63) >> 6;
#pragma unroll
    for (int i = 0; i < 4; ++i) {
        int j = t * 4 + i;
        bias_c[b * 1024 + j] = (j < cntf) ? 0.f : -14427.0f;
    }
    if (t == 0) {
        meta[b * 4 + 0] = cntf;
        meta[b * 4 + 1] = ntiles;
        meta[b * 4 + 2] = ntiles << 6;
        meta[b * 4 + 3] = __float_as_int(cnt ? 1.f : 0.f);
    }
}

// ---------------- fused Q + compacted-KV GEMM ----------------
// id<512: Q path (hsb@wqb^T -> qb). id>=512: KV path over COMPACTED pooled rows:
// lid=id-512: b=lid>>7, rowtile rt=(lid>>4)&7, coltile ct=lid&15. A-rows gathered
// via idxl (pads duplicate last valid row -> finite, zeroed later by bias_c).
// Blocks with rowBase >= cntp64 exit immediately (typically 224 of 256).
__global__ __launch_bounds__(256)
void gemm_fused(const __bf16* __restrict__ hsb, const __bf16* __restrict__ poolb,
                const __bf16* __restrict__ wqb, const __bf16* __restrict__ wkvb,
                const float* __restrict__ bq, const float* __restrict__ bk,
                const float* __restrict__ bv, float qscale,
                const int* __restrict__ idxl, const int* __restrict__ meta,
                __bf16* __restrict__ qb, __bf16* __restrict__ kb,
                __bf16* __restrict__ vtb) {
    __shared__ __bf16 As[128 * 64];
    __shared__ __bf16 Bs[128 * 64];
    const int tid  = threadIdx.x;
    const int lane = tid & 63, wid = tid >> 6;
    const int lg = lane >> 4, l15 = lane & 15;
    const int wm = (wid >> 1) * 64, wn = (wid & 1) * 64;

    const int id = blockIdx.x;
    const bool isQ = (id < 512);
    int bx, by, bB = 0, cntf = 0;
    if (isQ) { bx = id & 63; by = id >> 6; }
    else {
        int lid = id - 512;
        bB = lid >> 7;
        bx = (lid >> 4) & 7;
        by = lid & 15;
        if (bx * 128 >= meta[bB * 4 + 2]) return;   // beyond needed compact rows
        cntf = meta[bB * 4 + 0];
    }
    const int rowBase = bx * 128, colBase = by * 128;

    const f32x4 zero = {0.f, 0.f, 0.f, 0.f};
    f32x4 acc[4][4];
#pragma unroll
    for (int m = 0; m < 4; ++m)
#pragma unroll
        for (int n = 0; n < 4; ++n) acc[m][n] = zero;

    const __bf16* W = isQ ? wqb : wkvb;
    const char* Wg = (const char*)(W + (size_t)colBase * 1024);
    char* AsB = (char*)As;
    char* BsB = (char*)Bs;

    const char* ag[4]; const char* wg[4]; int ld[4];
#pragma unroll
    for (int p = 0; p < 4; ++p) {
        int o  = p * 4096 + tid * 16;
        int r  = o >> 7, cb = o & 127;
        int cs = cb ^ ((r & 7) << 4);
        if (isQ) {
            ag[p] = (const char*)(hsb + (size_t)(rowBase + r) * 1024) + cs;
        } else {
            int rg   = rowBase + r;
            int idxg = idxl[bB * 1024 + (rg < cntf ? rg : cntf - 1)];
            ag[p] = (const char*)(poolb + (size_t)(bB * 1024 + idxg) * 1024) + cs;
        }
        wg[p] = Wg + (size_t)r * 2048 + cs;
        ld[p] = o;
    }

    for (int kt = 0; kt < 16; ++kt) {
        const int k0b = kt * 128;
        __syncthreads();
#pragma unroll
        for (int p = 0; p < 4; ++p) {
            gload16(ag[p] + k0b, AsB + ld[p]);
            gload16(wg[p] + k0b, BsB + ld[p]);
        }
        __syncthreads();

        bf16x8 af[4][2], bfr[4][2];
#pragma unroll
        for (int m = 0; m < 4; ++m)
#pragma unroll
            for (int kk = 0; kk < 2; ++kk) {
                int r  = wm + m * 16 + l15;
                int cb = kk * 64 + lg * 16;
                af[m][kk] = *(const bf16x8*)(AsB + r * 128 + (cb ^ ((r & 7) << 4)));
            }
#pragma unroll
        for (int n = 0; n < 4; ++n)
#pragma unroll
            for (int kk = 0; kk < 2; ++kk) {
                int r  = wn + n * 16 + l15;
                int cb = kk * 64 + lg * 16;
                bfr[n][kk] = *(const bf16x8*)(BsB + r * 128 + (cb ^ ((r & 7) << 4)));
            }
#pragma unroll
        for (int m = 0; m < 4; ++m)
#pragma unroll
            for (int n = 0; n < 4; ++n) {
                acc[m][n] = mfma16(af[m][0], bfr[n][0], acc[m][n]);
                acc[m][n] = mfma16(af[m][1], bfr[n][1], acc[m][n]);
            }
    }

    // epilogue. C layout: col = lane&15, row = (lane>>4)*4 + reg
#pragma unroll
    for (int m = 0; m < 4; ++m)
#pragma unroll
        for (int n = 0; n < 4; ++n) {
            int col  = colBase + wn + n * 16 + l15;
            int row0 = rowBase + wm + m * 16 + lg * 4;
            if (isQ) {
                float bvl = bq[col] * qscale;
#pragma unroll
                for (int reg = 0; reg < 4; ++reg)
                    qb[(size_t)(row0 + reg) * 1024 + col] = (__bf16)(acc[m][n][reg] + bvl);
            } else if (col < 1024) {
                float bvl = bk[col];
#pragma unroll
                for (int reg = 0; reg < 4; ++reg)
                    kb[(size_t)(bB * 1024 + row0 + reg) * 1024 + col] = (__bf16)(acc[m][n][reg] + bvl);
            } else {
                float bvl = bv[col - 1024];
                bf16x4 o;
#pragma unroll
                for (int reg = 0; reg < 4; ++reg) o[reg] = (__bf16)(acc[m][n][reg] + bvl);
                *reinterpret_cast<bf16x4*>(vtb + ((size_t)(bB * 1024 + (col - 1024)) << 10) + row0) = o;
            }
        }
}

// ---------------- flash attention over COMPACTED keys ----------------
// Round-3 verified structure (4 waves x 64 q, 16x16x32, LDS-P, absmax 1.95e-3).
// Changes: K/V bases -> compacted buffers, dynamic tile count ntiles (typ. 1-2),
// mask bias -> tail-validity bias from bias_c, s scaled by sscale (0 only in the
// all-masked fallback -> P=1 uniform, exact).
__global__ __launch_bounds__(256, 2)
void attn_kernel(const __bf16* __restrict__ Q, const __bf16* __restrict__ K,
                 const __bf16* __restrict__ Vt, const float* __restrict__ bias_c,
                 const int* __restrict__ meta, float* __restrict__ out) {
    __shared__ __bf16 Ks[2][64 * 64];
    __shared__ __bf16 Vs[2][64 * 64];
    __shared__ __bf16 Ps[4][64 * 64];
    const int tid  = threadIdx.x;
    const int lane = tid & 63, wid = tid >> 6;
    const int lg = lane >> 4, l15 = lane & 15;

    // XCD-aware bijective swizzle (512 blocks, 64 consecutive per XCD)
    const int lin = blockIdx.x + blockIdx.y * 16;
    const int nid = (lin & 7) * 64 + (lin >> 3);
    const int qi = nid & 15, bh = nid >> 4;
    const int b = bh >> 4, h = bh & 15;
    const int qbase = qi * 256;

    const int   ntile  = meta[b * 4 + 1];
    const float sscale = __int_as_float(meta[b * 4 + 3]);

    // Q fragments: 4 sub-tiles of 16 q rows each (A layout: row=l15, k=lg*8+j)
    bf16x8 aq[4][2];
#pragma unroll
    for (int qm = 0; qm < 4; ++qm) {
        const __bf16* qrow = Q + (((size_t)(b * 4096 + qbase + wid * 64 + qm * 16 + l15)) << 10) + h * 64;
        aq[qm][0] = *(const bf16x8*)(qrow + lg * 8);
        aq[qm][1] = *(const bf16x8*)(qrow + 32 + lg * 8);
    }

    const f32x4 zero = {0.f, 0.f, 0.f, 0.f};
    f32x4 acc[4][4];
#pragma unroll
    for (int qm = 0; qm < 4; ++qm)
#pragma unroll
        for (int n = 0; n < 4; ++n) acc[qm][n] = zero;
    float rs[4] = {0.f, 0.f, 0.f, 0.f};

    const char* Kg = (const char*)(K + (((size_t)(b * 1024)) << 10) + h * 64);
    const char* Vg = (const char*)(Vt + (((size_t)(b * 1024 + h * 64)) << 10));
    const float* mbp = bias_c + b * 1024;

    char* PsB = (char*)Ps[wid];
    const int pswz = (l15 & 7) << 4;

    const char* kg[2]; const char* vg[2]; int ld[2];
#pragma unroll
    for (int p = 0; p < 2; ++p) {
        int o  = p * 4096 + tid * 16;
        int r  = o >> 7, cb = o & 127;
        int cs = cb ^ ((r & 7) << 4);
        kg[p] = Kg + (size_t)r * 2048 + cs;
        vg[p] = Vg + (size_t)r * 2048 + cs;
        ld[p] = o;
    }

#pragma unroll
    for (int p = 0; p < 2; ++p) {
        gload16(kg[p], (char*)Ks[0] + ld[p]);
        gload16(vg[p], (char*)Vs[0] + ld[p]);
    }

    int cur = 0;
    for (int kt = 0; kt < ntile; ++kt) {
        __syncthreads();   // buf[cur] ready (vmcnt drained at barrier), buf[cur^1] free
        if (kt + 1 < ntile) {
#pragma unroll
            for (int p = 0; p < 2; ++p) {
                gload16(kg[p] + (size_t)(kt + 1) * 131072, (char*)Ks[cur ^ 1] + ld[p]);
                gload16(vg[p] + (kt + 1) * 128,            (char*)Vs[cur ^ 1] + ld[p]);
            }
        }
        const char* KsB = (const char*)Ks[cur];
        const char* VsB = (const char*)Vs[cur];

        // K fragments (reused across 4 q sub-tiles)
        bf16x8 bk[4][2];
#pragma unroll
        for (int n = 0; n < 4; ++n)
#pragma unroll
            for (int kk = 0; kk < 2; ++kk) {
                int key = n * 16 + l15;
                bk[n][kk] = *(const bf16x8*)(KsB + key * 128 + ((kk * 64 + lg * 16) ^ ((key & 7) << 4)));
            }
        f32x4 mv[4];
#pragma unroll
        for (int n = 0; n < 4; ++n) mv[n] = *(const f32x4*)(mbp + kt * 64 + n * 16 + lg * 4);

        // per q sub-tile: S^T = K·Q^T (col=q=l15, row=key=lg*4+reg), exp2, write P
#pragma unroll
        for (int qm = 0; qm < 4; ++qm) {
            f32x4 s[4];
#pragma unroll
            for (int n = 0; n < 4; ++n) {
                s[n] = mfma16(bk[n][0], aq[qm][0], zero);
                s[n] = mfma16(bk[n][1], aq[qm][1], s[n]);
            }
            const int prow = (qm * 16 + l15) * 128;
#pragma unroll
            for (int n = 0; n < 4; ++n) {
                float p0 = fast_exp2(fmaf(s[n][0], sscale, mv[n][0]));
                float p1 = fast_exp2(fmaf(s[n][1], sscale, mv[n][1]));
                float p2 = fast_exp2(fmaf(s[n][2], sscale, mv[n][2]));
                float p3 = fast_exp2(fmaf(s[n][3], sscale, mv[n][3]));
                rs[qm] += (p0 + p1) + (p2 + p3);
                bf16x4 o;
                o[0] = (__bf16)p0; o[1] = (__bf16)p1; o[2] = (__bf16)p2; o[3] = (__bf16)p3;
                *(bf16x4*)(PsB + prow + ((n * 32 + lg * 8) ^ pswz)) = o;
            }
        }

        // V fragments (reused across 4 q sub-tiles)
        bf16x8 bv[4][2];
#pragma unroll
        for (int n = 0; n < 4; ++n)
#pragma unroll
            for (int kk = 0; kk < 2; ++kk) {
                int d = n * 16 + l15;
                bv[n][kk] = *(const bf16x8*)(VsB + d * 128 + ((kk * 64 + lg * 16) ^ ((d & 7) << 4)));
            }
#pragma unroll
        for (int qm = 0; qm < 4; ++qm) {
            const int prow = (qm * 16 + l15) * 128;
            bf16x8 ap0 = *(const bf16x8*)(PsB + prow + ((lg * 16) ^ pswz));
            bf16x8 ap1 = *(const bf16x8*)(PsB + prow + ((64 + lg * 16) ^ pswz));
#pragma unroll
            for (int n = 0; n < 4; ++n) {
                acc[qm][n] = mfma16(ap0, bv[n][0], acc[qm][n]);
                acc[qm][n] = mfma16(ap1, bv[n][1], acc[qm][n]);
            }
        }
        cur ^= 1;
    }

    // reduce row sums over the 4 lane-groups, redistribute to epilogue layout
    float inv[4][4];
#pragma unroll
    for (int qm = 0; qm < 4; ++qm) {
        rs[qm] += __shfl_xor(rs[qm], 16);
        rs[qm] += __shfl_xor(rs[qm], 32);
#pragma unroll
        for (int r = 0; r < 4; ++r) inv[qm][r] = 1.0f / __shfl(rs[qm], lg * 4 + r);
    }

#pragma unroll
    for (int qm = 0; qm < 4; ++qm)
#pragma unroll
        for (int n = 0; n < 4; ++n)
#pragma unroll
            for (int r = 0; r < 4; ++r) {
                size_t row = (size_t)(b * 4096 + qbase + wid * 64 + qm * 16 + lg * 4 + r);
                out[(row << 10) + h * 64 + n * 16 + l15] = acc[qm][n][r] * inv[qm][r];
            }
}

extern "C" void kernel_launch(void* const* d_in, const int* in_sizes, int n_in,
                              void* d_out, int out_size, void* d_ws, size_t ws_size,
                              hipStream_t stream) {
    const float* hs    = (const float*)d_in[0];
    const int*   amask = (const int*)d_in[1];
    const float* Wq    = (const float*)d_in[2];
    const float* bq    = (const float*)d_in[3];
    const float* Wk    = (const float*)d_in[4];
    const float* bk    = (const float*)d_in[5];
    const float* Wv    = (const float*)d_in[6];
    const float* bv    = (const float*)d_in[7];
    float* out = (float*)d_out;

    char* ws = (char*)d_ws;
    size_t off = 0;
    auto alloc = [&](size_t bytes) -> char* {
        char* p = ws + off;
        off += (bytes + 255) & ~(size_t)255;
        return p;
    };
    __bf16* hsb   = (__bf16*)alloc(8388608ull * 2);  // hidden bf16 [8192][1024]
    __bf16* qb    = (__bf16*)alloc(8388608ull * 2);  // Q bf16 (pre-scaled)
    __bf16* poolb = (__bf16*)alloc(2097152ull * 2);  // pooled bf16 [2048][1024]
    __bf16* kb    = (__bf16*)alloc(2097152ull * 2);  // K compact [b][key_c][1024]
    __bf16* vtb   = (__bf16*)alloc(2097152ull * 2);  // V^T compact [b][h*64+d][key_c]
    __bf16* wqb   = (__bf16*)alloc(1048576ull * 2);  // Wq * qscale
    __bf16* wkvb  = (__bf16*)alloc(2097152ull * 2);  // [Wk ; Wv]
    int*    idxl  = (int*)alloc(2048 * 4);           // compact index lists
    float*  biasc = (float*)alloc(2048 * 4);         // tail-validity bias
    int*    meta  = (int*)alloc(8 * 4);

    const float qscale = 0.125f * LOG2E;   // 1/sqrt(DH) and log2(e) folded into Q

    cast_pool_kernel<<<1024, 256, 0, stream>>>(hs, hsb, poolb, 262144);
    cast_w_kernel<<<1536, 256, 0, stream>>>(Wq, Wk, Wv, wqb, wkvb, qscale, 393216);
    maskscan_kernel<<<2, 256, 0, stream>>>(amask, idxl, biasc, meta);

    gemm_fused<<<768, 256, 0, stream>>>(hsb, poolb, wqb, wkvb, bq, bk, bv, qscale,
                                        idxl, meta, qb, kb, vtb);

    attn_kernel<<<dim3(16, 32), 256, 0, stream>>>(qb, kb, vtb, biasc, meta, out);
}